// Round 2
// baseline (2336.081 us; speedup 1.0000x reference)
//
#include <hip/hip_runtime.h>
#include <math.h>

#define NSCALE 0.44668359215096315f

__device__ __forceinline__ float eluf(float v)  { return v > 0.0f ? v : __expf(v) - 1.0f; }
__device__ __forceinline__ float reluf(float v) { return fmaxf(v, 0.0f); }

// ---------------- Kernel A: encoder -> z, per-block partial sums, optional z store ----------------
__global__ __launch_bounds__(256) void kA(const float* __restrict__ x,
                                          const float* __restrict__ ew1, const float* __restrict__ eb1,
                                          const float* __restrict__ ew2, const float* __restrict__ eb2,
                                          float* __restrict__ partials, float* __restrict__ zbuf,
                                          int B, int storez)
{
    __shared__ float W[544];
    __shared__ float wsum[4][32];
    int tid = threadIdx.x;
    // stage encoder weights: ew1[256], eb1[16], ew2[256], eb2[16]
    if (tid < 256) W[tid] = ew1[tid];
    if (tid < 16)  W[256 + tid] = eb1[tid];
    if (tid < 256) W[272 + tid] = ew2[tid];
    if (tid < 16)  W[528 + tid] = eb2[tid];
    __syncthreads();

    int i = blockIdx.x * 256 + tid;
    bool valid = i < B;
    float xv[16];
    if (valid) {
        const float4* xp = reinterpret_cast<const float4*>(x + (size_t)i * 16);
#pragma unroll
        for (int q = 0; q < 4; ++q) {
            float4 v = xp[q];
            xv[4*q+0] = v.x; xv[4*q+1] = v.y; xv[4*q+2] = v.z; xv[4*q+3] = v.w;
        }
    } else {
#pragma unroll
        for (int q = 0; q < 16; ++q) xv[q] = 0.0f;
    }

    float h1[16];
#pragma unroll
    for (int o = 0; o < 16; ++o) {
        float a = W[256 + o];
#pragma unroll
        for (int k = 0; k < 16; ++k) a = fmaf(xv[k], W[o*16+k], a);
        h1[o] = eluf(a);
    }
    float z[16];
#pragma unroll
    for (int o = 0; o < 16; ++o) {
        float a = W[528 + o];
#pragma unroll
        for (int k = 0; k < 16; ++k) a = fmaf(h1[k], W[272 + o*16+k], a);
        z[o] = valid ? a : 0.0f;
    }

    if (storez && valid) {
        float4* zp = reinterpret_cast<float4*>(zbuf + (size_t)i * 16);
        zp[0] = make_float4(z[0],  z[1],  z[2],  z[3]);
        zp[1] = make_float4(z[4],  z[5],  z[6],  z[7]);
        zp[2] = make_float4(z[8],  z[9],  z[10], z[11]);
        zp[3] = make_float4(z[12], z[13], z[14], z[15]);
    }

    int lane = tid & 63, wave = tid >> 6;
#pragma unroll
    for (int c = 0; c < 16; ++c) {
        float s = z[c];
        float q = z[c] * z[c];
#pragma unroll
        for (int m = 1; m < 64; m <<= 1) { s += __shfl_xor(s, m); q += __shfl_xor(q, m); }
        if (lane == 0) { wsum[wave][c] = s; wsum[wave][16 + c] = q; }
    }
    __syncthreads();
    if (tid < 32) {
        float t = wsum[0][tid] + wsum[1][tid] + wsum[2][tid] + wsum[3][tid];
        partials[(size_t)blockIdx.x * 32 + tid] = t;
    }
}

// ---------------- Kernel B: reduce partials -> BN affine ----------------
__global__ __launch_bounds__(256) void kB(const float* __restrict__ partials, int nblk, int B,
                                          const float* __restrict__ bng, const float* __restrict__ bnb,
                                          float* __restrict__ bnp)
{
    int tid = threadIdx.x;
    int q = tid >> 3, k = tid & 7;
    int chunk = (nblk + 7) / 8;
    int j0 = k * chunk;
    int j1 = j0 + chunk; if (j1 > nblk) j1 = nblk;
    double s = 0.0;
    for (int j = j0; j < j1; ++j) s += (double)partials[(size_t)j * 32 + q];
    s += __shfl_xor(s, 4);
    s += __shfl_xor(s, 2);
    s += __shfl_xor(s, 1);
    __shared__ double tot[32];
    if (k == 0) tot[q] = s;
    __syncthreads();
    if (tid < 16) {
        double mu  = tot[tid] / (double)B;
        double var = tot[16 + tid] / (double)B - mu * mu;
        double a = (double)bng[tid] / sqrt(var + 1e-5);
        double b = (double)bnb[tid] - mu * a;
        bnp[tid]      = (float)a;
        bnp[16 + tid] = (float)b;
    }
}

// ---------------- LDS layout for kC (float offsets, all 16B-aligned) ----------------
constexpr int OFF_BNP  = 0;      // 32
constexpr int OFF_PC1W = 32;     // 64
constexpr int OFF_PC1B = 96;     // 16
constexpr int OFF_PC2W = 112;    // 512  swizzled [tap][o][ci]
constexpr int OFF_PC2B = 624;    // 16
constexpr int OFF_PC3W = 640;    // 512  direct [o][ci][tap]
constexpr int OFF_PC3B = 1152;   // 16
constexpr int OFF_PC4W = 1168;   // 256
constexpr int OFF_PC4B = 1424;   // 16
constexpr int OFF_PC5W = 1440;   // 768  swizzled [g][o][ci]
constexpr int OFF_PC5B = 2208;   // 16
constexpr int OFF_PLW  = 2224;   // 256
constexpr int OFF_PLB  = 2480;   // 16
constexpr int OFF_DC1W = 2496;   // 8
constexpr int OFF_DC1B = 2504;   // 8
constexpr int OFF_DC2W = 2512;   // 128  direct [c][ci][tap]
constexpr int OFF_DC2B = 2640;   // 8
constexpr int OFF_DC3W = 2648;   // 64
constexpr int OFF_DC3B = 2712;   // 8
constexpr int OFF_DC4W = 2720;   // 64
constexpr int OFF_DC4B = 2784;   // 8
constexpr int OFF_DL1W = 2792;   // 1024 swizzled [o][t][c]
constexpr int OFF_DL1B = 3816;   // 16
constexpr int OFF_DL2W = 3832;   // 256
constexpr int OFF_DL2B = 4088;   // 16
constexpr int OFF_DL3W = 4104;   // 256
constexpr int OFF_DL3B = 4360;   // 16
constexpr int OFF_EW1  = 4376;   // 256 (RECOMPUTE only)
constexpr int OFF_EB1  = 4632;   // 16
constexpr int OFF_EW2  = 4648;   // 256
constexpr int OFF_EB2  = 4904;   // 16
constexpr int LDS_TOT  = 4920;

// ---------------- Kernel C: full per-element pipeline, weights in LDS ----------------
template<bool RECOMPUTE>
__global__ __launch_bounds__(256, 3) void kC(
    const float* __restrict__ x, const float* __restrict__ zbuf,
    const float* __restrict__ noise, const float* __restrict__ fading,
    const float* __restrict__ ew1, const float* __restrict__ eb1,
    const float* __restrict__ ew2, const float* __restrict__ eb2,
    const float* __restrict__ bnp,
    const float* __restrict__ pc1w, const float* __restrict__ pc1b,
    const float* __restrict__ pc2w, const float* __restrict__ pc2b,
    const float* __restrict__ pc3w, const float* __restrict__ pc3b,
    const float* __restrict__ pc4w, const float* __restrict__ pc4b,
    const float* __restrict__ pc5w, const float* __restrict__ pc5b,
    const float* __restrict__ plw,  const float* __restrict__ plb,
    const float* __restrict__ dc1w, const float* __restrict__ dc1b,
    const float* __restrict__ dc2w, const float* __restrict__ dc2b,
    const float* __restrict__ dc3w, const float* __restrict__ dc3b,
    const float* __restrict__ dc4w, const float* __restrict__ dc4b,
    const float* __restrict__ dl1w, const float* __restrict__ dl1b,
    const float* __restrict__ dl2w, const float* __restrict__ dl2b,
    const float* __restrict__ dl3w, const float* __restrict__ dl3b,
    float* __restrict__ out, int B)
{
    __shared__ float W[LDS_TOT];
    int tid = threadIdx.x;

    // ---- stage weights into LDS (one-time per block) ----
    {
        if (tid < 32)  W[OFF_BNP + tid] = bnp[tid];
        if (tid < 64)  W[OFF_PC1W + tid] = pc1w[tid];
        if (tid < 16)  W[OFF_PC1B + tid] = pc1b[tid];
        for (int j = tid; j < 512; j += 256) {               // pc2 swizzle -> [tap][o][ci]
            int o = j >> 5, r = j & 31, ci = r >> 1, tap = r & 1;
            W[OFF_PC2W + tap*256 + o*16 + ci] = pc2w[j];
        }
        if (tid < 16)  W[OFF_PC2B + tid] = pc2b[tid];
        for (int j = tid; j < 512; j += 256) W[OFF_PC3W + j] = pc3w[j];
        if (tid < 16)  W[OFF_PC3B + tid] = pc3b[tid];
        if (tid < 256) W[OFF_PC4W + tid] = pc4w[tid];
        if (tid < 16)  W[OFF_PC4B + tid] = pc4b[tid];
        for (int j = tid; j < 768; j += 256) {               // pc5 swizzle -> [g][o][ci]
            int o = j / 48, r = j - o*48, ci = r / 3, g = r - ci*3;
            W[OFF_PC5W + g*256 + o*16 + ci] = pc5w[j];
        }
        if (tid < 16)  W[OFF_PC5B + tid] = pc5b[tid];
        if (tid < 256) W[OFF_PLW + tid] = plw[tid];
        if (tid < 16)  W[OFF_PLB + tid] = plb[tid];
        if (tid < 8)   W[OFF_DC1W + tid] = dc1w[tid];
        if (tid < 8)   W[OFF_DC1B + tid] = dc1b[tid];
        if (tid < 128) W[OFF_DC2W + tid] = dc2w[tid];
        if (tid < 8)   W[OFF_DC2B + tid] = dc2b[tid];
        if (tid < 64)  W[OFF_DC3W + tid] = dc3w[tid];
        if (tid < 8)   W[OFF_DC3B + tid] = dc3b[tid];
        if (tid < 64)  W[OFF_DC4W + tid] = dc4w[tid];
        if (tid < 8)   W[OFF_DC4B + tid] = dc4b[tid];
        for (int j = tid; j < 1024; j += 256) {              // dl1 swizzle -> [o][t][c]
            int o = j >> 6, r = j & 63, c = r >> 3, t = r & 7;
            W[OFF_DL1W + o*64 + t*8 + c] = dl1w[j];
        }
        if (tid < 16)  W[OFF_DL1B + tid] = dl1b[tid];
        if (tid < 256) W[OFF_DL2W + tid] = dl2w[tid];
        if (tid < 16)  W[OFF_DL2B + tid] = dl2b[tid];
        if (tid < 256) W[OFF_DL3W + tid] = dl3w[tid];
        if (tid < 16)  W[OFF_DL3B + tid] = dl3b[tid];
        if (RECOMPUTE) {
            if (tid < 256) W[OFF_EW1 + tid] = ew1[tid];
            if (tid < 16)  W[OFF_EB1 + tid] = eb1[tid];
            if (tid < 256) W[OFF_EW2 + tid] = ew2[tid];
            if (tid < 16)  W[OFF_EB2 + tid] = eb2[tid];
        }
    }
    __syncthreads();

    int i = blockIdx.x * 256 + tid;
    if (i >= B) return;

    // ---- z (load or recompute) + BN affine ----
    float zn[16];
    if (RECOMPUTE) {
        float xv[16];
        const float4* xp = reinterpret_cast<const float4*>(x + (size_t)i * 16);
#pragma unroll
        for (int q = 0; q < 4; ++q) {
            float4 v = xp[q];
            xv[4*q+0] = v.x; xv[4*q+1] = v.y; xv[4*q+2] = v.z; xv[4*q+3] = v.w;
        }
        float h1[16];
#pragma unroll
        for (int o = 0; o < 16; ++o) {
            float a = W[OFF_EB1 + o];
#pragma unroll
            for (int k = 0; k < 16; ++k) a = fmaf(xv[k], W[OFF_EW1 + o*16+k], a);
            h1[o] = eluf(a);
        }
#pragma unroll
        for (int o = 0; o < 16; ++o) {
            float a = W[OFF_EB2 + o];
#pragma unroll
            for (int k = 0; k < 16; ++k) a = fmaf(h1[k], W[OFF_EW2 + o*16+k], a);
            zn[o] = fmaf(a, W[OFF_BNP + o], W[OFF_BNP + 16 + o]);
        }
    } else {
        const float4* zp = reinterpret_cast<const float4*>(zbuf + (size_t)i * 16);
#pragma unroll
        for (int q = 0; q < 4; ++q) {
            float4 v = zp[q];
            zn[4*q+0] = fmaf(v.x, W[OFF_BNP + 4*q+0], W[OFF_BNP + 16 + 4*q+0]);
            zn[4*q+1] = fmaf(v.y, W[OFF_BNP + 4*q+1], W[OFF_BNP + 16 + 4*q+1]);
            zn[4*q+2] = fmaf(v.z, W[OFF_BNP + 4*q+2], W[OFF_BNP + 16 + 4*q+2]);
            zn[4*q+3] = fmaf(v.w, W[OFF_BNP + 4*q+3], W[OFF_BNP + 16 + 4*q+3]);
        }
    }

    // ---- channel: 3-tap causal complex FIR + AWGN ----
    float f[6];
    {
        const float2* fp = reinterpret_cast<const float2*>(fading + (size_t)i * 6);
#pragma unroll
        for (int q = 0; q < 3; ++q) { float2 v = fp[q]; f[2*q] = v.x; f[2*q+1] = v.y; }
    }
    float cr[16];
#pragma unroll
    for (int n = 0; n < 8; ++n) {
        float re = f[0]*zn[2*n]   - f[1]*zn[2*n+1];
        float im = f[0]*zn[2*n+1] + f[1]*zn[2*n];
        if (n >= 1) { re += f[2]*zn[2*n-2] - f[3]*zn[2*n-1];
                      im += f[2]*zn[2*n-1] + f[3]*zn[2*n-2]; }
        if (n >= 2) { re += f[4]*zn[2*n-4] - f[5]*zn[2*n-3];
                      im += f[4]*zn[2*n-3] + f[5]*zn[2*n-4]; }
        cr[2*n] = re; cr[2*n+1] = im;
    }
    {
        const float4* np_ = reinterpret_cast<const float4*>(noise + (size_t)i * 16);
#pragma unroll
        for (int q = 0; q < 4; ++q) {
            float4 v = np_[q];
            cr[4*q+0] = fmaf(v.x, NSCALE, cr[4*q+0]);
            cr[4*q+1] = fmaf(v.y, NSCALE, cr[4*q+1]);
            cr[4*q+2] = fmaf(v.z, NSCALE, cr[4*q+2]);
            cr[4*q+3] = fmaf(v.w, NSCALE, cr[4*q+3]);
        }
    }

    // ---- p-convs ----
    float p5a[16];
#pragma unroll
    for (int o = 0; o < 16; ++o) p5a[o] = W[OFF_PC5B + o];

#pragma unroll
    for (int g = 0; g < 3; ++g) {
        float p2a[2][16];
#pragma unroll
        for (int c2 = 0; c2 < 2; ++c2)
#pragma unroll
            for (int o = 0; o < 16; ++o) p2a[c2][o] = W[OFF_PC2B + o];

#pragma unroll
        for (int t = 0; t < 3; ++t) {
            float p1[16];
#pragma unroll
            for (int o = 0; o < 16; ++o) {
                float a = W[OFF_PC1B + o];
#pragma unroll
                for (int k = 0; k < 4; ++k) a = fmaf(W[OFF_PC1W + o*4+k], cr[4*g + t + k], a);
                p1[o] = reluf(a);
            }
#pragma unroll
            for (int tap = 0; tap < 2; ++tap) {
                const int c2 = t - tap;
                if (c2 < 0 || c2 > 1) continue;
#pragma unroll
                for (int o = 0; o < 16; ++o) {
                    float a = p2a[c2][o];
#pragma unroll
                    for (int ci = 0; ci < 16; ++ci)
                        a = fmaf(W[OFF_PC2W + tap*256 + o*16 + ci], p1[ci], a);
                    p2a[c2][o] = a;
                }
            }
        }
#pragma unroll
        for (int c2 = 0; c2 < 2; ++c2)
#pragma unroll
            for (int o = 0; o < 16; ++o) p2a[c2][o] = reluf(p2a[c2][o]);

        float p3[16];
#pragma unroll
        for (int o = 0; o < 16; ++o) {
            float a = W[OFF_PC3B + o];
#pragma unroll
            for (int ci = 0; ci < 16; ++ci) {
                a = fmaf(W[OFF_PC3W + o*32 + ci*2 + 0], p2a[0][ci], a);
                a = fmaf(W[OFF_PC3W + o*32 + ci*2 + 1], p2a[1][ci], a);
            }
            p3[o] = reluf(a);
        }
        float p4[16];
#pragma unroll
        for (int o = 0; o < 16; ++o) {
            float a = W[OFF_PC4B + o];
#pragma unroll
            for (int ci = 0; ci < 16; ++ci) a = fmaf(W[OFF_PC4W + o*16 + ci], p3[ci], a);
            p4[o] = reluf(a);
        }
#pragma unroll
        for (int o = 0; o < 16; ++o) {
            float a = p5a[o];
#pragma unroll
            for (int ci = 0; ci < 16; ++ci)
                a = fmaf(W[OFF_PC5W + g*256 + o*16 + ci], p4[ci], a);
            p5a[o] = a;
        }
    }

    float hh[16];
    {
        float p5r[16];
#pragma unroll
        for (int o = 0; o < 16; ++o) p5r[o] = reluf(p5a[o]);
#pragma unroll
        for (int o = 0; o < 16; ++o) {
            float a = W[OFF_PLB + o];
#pragma unroll
            for (int ci = 0; ci < 16; ++ci) a = fmaf(W[OFF_PLW + o*16 + ci], p5r[ci], a);
            hh[o] = a;
        }
    }

    // ---- complex equalizer t = cc / hh ----
    float tr[16];
#pragma unroll
    for (int n = 0; n < 8; ++n) {
        float a = cr[2*n], b = cr[2*n+1];
        float c = hh[2*n], d = hh[2*n+1];
        float inv = 1.0f / (c*c + d*d);
        tr[2*n]   = (a*c + b*d) * inv;
        tr[2*n+1] = (b*c - a*d) * inv;
    }

    // ---- d-convs, streamed column-wise into dl1 accumulation ----
    float y[16];
#pragma unroll
    for (int o = 0; o < 16; ++o) y[o] = W[OFF_DL1B + o];
#pragma unroll
    for (int t = 0; t < 8; ++t) {
        float d1a[8], d1b[8];
#pragma unroll
        for (int c = 0; c < 8; ++c) {
            d1a[c] = reluf(fmaf(W[OFF_DC1W + c], tr[2*t+0], W[OFF_DC1B + c]));
            d1b[c] = reluf(fmaf(W[OFF_DC1W + c], tr[2*t+1], W[OFF_DC1B + c]));
        }
        float d2[8];
#pragma unroll
        for (int c = 0; c < 8; ++c) {
            float a = W[OFF_DC2B + c];
#pragma unroll
            for (int ci = 0; ci < 8; ++ci) {
                a = fmaf(W[OFF_DC2W + c*16 + ci*2 + 0], d1a[ci], a);
                a = fmaf(W[OFF_DC2W + c*16 + ci*2 + 1], d1b[ci], a);
            }
            d2[c] = reluf(a);
        }
        float d3[8];
#pragma unroll
        for (int c = 0; c < 8; ++c) {
            float a = W[OFF_DC3B + c];
#pragma unroll
            for (int ci = 0; ci < 8; ++ci) a = fmaf(W[OFF_DC3W + c*8 + ci], d2[ci], a);
            d3[c] = reluf(a);
        }
        float d4[8];
#pragma unroll
        for (int c = 0; c < 8; ++c) {
            float a = W[OFF_DC4B + c];
#pragma unroll
            for (int ci = 0; ci < 8; ++ci) a = fmaf(W[OFF_DC4W + c*8 + ci], d3[ci], a);
            d4[c] = reluf(a);
        }
#pragma unroll
        for (int o = 0; o < 16; ++o) {
            float a = y[o];
#pragma unroll
            for (int c = 0; c < 8; ++c) a = fmaf(W[OFF_DL1W + o*64 + t*8 + c], d4[c], a);
            y[o] = a;
        }
    }
#pragma unroll
    for (int o = 0; o < 16; ++o) y[o] = reluf(y[o]);
    float h2[16];
#pragma unroll
    for (int o = 0; o < 16; ++o) {
        float a = W[OFF_DL2B + o];
#pragma unroll
        for (int ci = 0; ci < 16; ++ci) a = fmaf(W[OFF_DL2W + o*16 + ci], y[ci], a);
        h2[o] = eluf(a);
    }
    float o16[16];
#pragma unroll
    for (int o = 0; o < 16; ++o) {
        float a = W[OFF_DL3B + o];
#pragma unroll
        for (int ci = 0; ci < 16; ++ci) a = fmaf(W[OFF_DL3W + o*16 + ci], h2[ci], a);
        o16[o] = a;
    }
    float4* op = reinterpret_cast<float4*>(out + (size_t)i * 16);
    op[0] = make_float4(o16[0],  o16[1],  o16[2],  o16[3]);
    op[1] = make_float4(o16[4],  o16[5],  o16[6],  o16[7]);
    op[2] = make_float4(o16[8],  o16[9],  o16[10], o16[11]);
    op[3] = make_float4(o16[12], o16[13], o16[14], o16[15]);
}

extern "C" void kernel_launch(void* const* d_in, const int* in_sizes, int n_in,
                              void* d_out, int out_size, void* d_ws, size_t ws_size,
                              hipStream_t stream)
{
    const float* x      = (const float*)d_in[0];
    const float* noise  = (const float*)d_in[1];
    const float* fading = (const float*)d_in[2];
    const float* ew1  = (const float*)d_in[3];
    const float* eb1  = (const float*)d_in[4];
    const float* ew2  = (const float*)d_in[5];
    const float* eb2  = (const float*)d_in[6];
    const float* bng  = (const float*)d_in[7];
    const float* bnb  = (const float*)d_in[8];
    const float* pc1w = (const float*)d_in[9];
    const float* pc1b = (const float*)d_in[10];
    const float* pc2w = (const float*)d_in[11];
    const float* pc2b = (const float*)d_in[12];
    const float* pc3w = (const float*)d_in[13];
    const float* pc3b = (const float*)d_in[14];
    const float* pc4w = (const float*)d_in[15];
    const float* pc4b = (const float*)d_in[16];
    const float* pc5w = (const float*)d_in[17];
    const float* pc5b = (const float*)d_in[18];
    const float* plw  = (const float*)d_in[19];
    const float* plb  = (const float*)d_in[20];
    const float* dc1w = (const float*)d_in[21];
    const float* dc1b = (const float*)d_in[22];
    const float* dc2w = (const float*)d_in[23];
    const float* dc2b = (const float*)d_in[24];
    const float* dc3w = (const float*)d_in[25];
    const float* dc3b = (const float*)d_in[26];
    const float* dc4w = (const float*)d_in[27];
    const float* dc4b = (const float*)d_in[28];
    const float* dl1w = (const float*)d_in[29];
    const float* dl1b = (const float*)d_in[30];
    const float* dl2w = (const float*)d_in[31];
    const float* dl2b = (const float*)d_in[32];
    const float* dl3w = (const float*)d_in[33];
    const float* dl3b = (const float*)d_in[34];

    int B = in_sizes[0] / 16;
    int nblk = (B + 255) / 256;

    float* partials = (float*)d_ws;                 // nblk*32 floats
    float* bnp = partials + (size_t)nblk * 32;      // 32 floats (scale, shift)
    float* zbuf = bnp + 32;                          // B*16 floats (optional)
    size_t need = ((size_t)nblk * 32 + 32 + (size_t)B * 16) * sizeof(float);
    int have_z = (ws_size >= need) ? 1 : 0;

    kA<<<nblk, 256, 0, stream>>>(x, ew1, eb1, ew2, eb2, partials, zbuf, B, have_z);
    kB<<<1, 256, 0, stream>>>(partials, nblk, B, bng, bnb, bnp);
    if (have_z) {
        kC<false><<<nblk, 256, 0, stream>>>(x, zbuf, noise, fading,
                                            ew1, eb1, ew2, eb2, bnp,
                                            pc1w, pc1b, pc2w, pc2b, pc3w, pc3b, pc4w, pc4b, pc5w, pc5b,
                                            plw, plb,
                                            dc1w, dc1b, dc2w, dc2b, dc3w, dc3b, dc4w, dc4b,
                                            dl1w, dl1b, dl2w, dl2b, dl3w, dl3b,
                                            (float*)d_out, B);
    } else {
        kC<true><<<nblk, 256, 0, stream>>>(x, zbuf, noise, fading,
                                           ew1, eb1, ew2, eb2, bnp,
                                           pc1w, pc1b, pc2w, pc2b, pc3w, pc3b, pc4w, pc4b, pc5w, pc5b,
                                           plw, plb,
                                           dc1w, dc1b, dc2w, dc2b, dc3w, dc3b, dc4w, dc4b,
                                           dl1w, dl1b, dl2w, dl2b, dl3w, dl3b,
                                           (float*)d_out, B);
    }
}

// Round 3
// 1982.825 us; speedup vs baseline: 1.1782x; 1.1782x over previous
//
#include <hip/hip_runtime.h>
#include <math.h>

#define NSCALE 0.44668359215096315f

__device__ __forceinline__ float eluf(float v)  { return v > 0.0f ? v : __expf(v) - 1.0f; }
__device__ __forceinline__ float reluf(float v) { return fmaxf(v, 0.0f); }

// ---------------- Kernel A: encoder -> z, per-block partial sums, z store ----------------
__global__ __launch_bounds__(256) void kA(const float* __restrict__ x,
                                          const float* __restrict__ ew1, const float* __restrict__ eb1,
                                          const float* __restrict__ ew2, const float* __restrict__ eb2,
                                          float* __restrict__ partials, float* __restrict__ zbuf,
                                          int B, int storez)
{
    __shared__ float W[544];
    __shared__ float wsum[4][32];
    int tid = threadIdx.x;
    if (tid < 256) W[tid] = ew1[tid];
    if (tid < 16)  W[256 + tid] = eb1[tid];
    if (tid < 256) W[272 + tid] = ew2[tid];
    if (tid < 16)  W[528 + tid] = eb2[tid];
    __syncthreads();

    int i = blockIdx.x * 256 + tid;
    bool valid = i < B;
    float xv[16];
    if (valid) {
        const float4* xp = reinterpret_cast<const float4*>(x + (size_t)i * 16);
#pragma unroll
        for (int q = 0; q < 4; ++q) {
            float4 v = xp[q];
            xv[4*q+0] = v.x; xv[4*q+1] = v.y; xv[4*q+2] = v.z; xv[4*q+3] = v.w;
        }
    } else {
#pragma unroll
        for (int q = 0; q < 16; ++q) xv[q] = 0.0f;
    }

    float h1[16];
#pragma unroll
    for (int o = 0; o < 16; ++o) {
        float a = W[256 + o];
#pragma unroll
        for (int k = 0; k < 16; ++k) a = fmaf(xv[k], W[o*16+k], a);
        h1[o] = eluf(a);
    }
    float z[16];
#pragma unroll
    for (int o = 0; o < 16; ++o) {
        float a = W[528 + o];
#pragma unroll
        for (int k = 0; k < 16; ++k) a = fmaf(h1[k], W[272 + o*16+k], a);
        z[o] = valid ? a : 0.0f;
    }

    if (storez && valid) {
        float4* zp = reinterpret_cast<float4*>(zbuf + (size_t)i * 16);
        zp[0] = make_float4(z[0],  z[1],  z[2],  z[3]);
        zp[1] = make_float4(z[4],  z[5],  z[6],  z[7]);
        zp[2] = make_float4(z[8],  z[9],  z[10], z[11]);
        zp[3] = make_float4(z[12], z[13], z[14], z[15]);
    }

    int lane = tid & 63, wave = tid >> 6;
#pragma unroll
    for (int c = 0; c < 16; ++c) {
        float s = z[c];
        float q = z[c] * z[c];
#pragma unroll
        for (int m = 1; m < 64; m <<= 1) { s += __shfl_xor(s, m); q += __shfl_xor(q, m); }
        if (lane == 0) { wsum[wave][c] = s; wsum[wave][16 + c] = q; }
    }
    __syncthreads();
    if (tid < 32) {
        float t = wsum[0][tid] + wsum[1][tid] + wsum[2][tid] + wsum[3][tid];
        partials[(size_t)blockIdx.x * 32 + tid] = t;
    }
}

// ---------------- Kernel B: reduce partials -> BN affine ----------------
__global__ __launch_bounds__(256) void kB(const float* __restrict__ partials, int nblk, int B,
                                          const float* __restrict__ bng, const float* __restrict__ bnb,
                                          float* __restrict__ bnp)
{
    int tid = threadIdx.x;
    int q = tid >> 3, k = tid & 7;
    int chunk = (nblk + 7) / 8;
    int j0 = k * chunk;
    int j1 = j0 + chunk; if (j1 > nblk) j1 = nblk;
    double s = 0.0;
    for (int j = j0; j < j1; ++j) s += (double)partials[(size_t)j * 32 + q];
    s += __shfl_xor(s, 4);
    s += __shfl_xor(s, 2);
    s += __shfl_xor(s, 1);
    __shared__ double tot[32];
    if (k == 0) tot[q] = s;
    __syncthreads();
    if (tid < 16) {
        double mu  = tot[tid] / (double)B;
        double var = tot[16 + tid] / (double)B - mu * mu;
        double a = (double)bng[tid] / sqrt(var + 1e-5);
        double b = (double)bnb[tid] - mu * a;
        bnp[tid]      = (float)a;
        bnp[16 + tid] = (float)b;
    }
}

// ---------------- LDS layout for kC ----------------
constexpr int OFF_BNP  = 0;      // 32
constexpr int OFF_PC1W = 32;     // 64   [o][k]
constexpr int OFF_PC1B = 96;     // 16
constexpr int OFF_PC2W = 112;    // 512  swizzled [tap][o][ci]
constexpr int OFF_PC2B = 624;    // 16
constexpr int OFF_PC3W = 640;    // 512  direct [o][ci][tap]
constexpr int OFF_PC3B = 1152;   // 16
constexpr int OFF_PC4W = 1168;   // 256
constexpr int OFF_PC4B = 1424;   // 16
constexpr int OFF_PC5W = 1440;   // 768  swizzled [g][o][ci]
constexpr int OFF_PC5B = 2208;   // 16
constexpr int OFF_PLW  = 2224;   // 256
constexpr int OFF_PLB  = 2480;   // 16
constexpr int OFF_DC1W = 2496;   // 8
constexpr int OFF_DC1B = 2504;   // 8
constexpr int OFF_DC2W = 2512;   // 128  direct [c][ci][tap]
constexpr int OFF_DC2B = 2640;   // 8
constexpr int OFF_DC3W = 2648;   // 64
constexpr int OFF_DC3B = 2712;   // 8
constexpr int OFF_DC4W = 2720;   // 64
constexpr int OFF_DC4B = 2784;   // 8
constexpr int OFF_DL1W = 2792;   // 1024 swizzled [o][t][c]
constexpr int OFF_DL1B = 3816;   // 16
constexpr int OFF_DL2W = 3832;   // 256
constexpr int OFF_DL2B = 4088;   // 16
constexpr int OFF_DL3W = 4104;   // 256
constexpr int OFF_DL3B = 4360;   // 16
constexpr int OFF_EW1  = 4376;   // 256 (RECOMPUTE only)
constexpr int OFF_EB1  = 4632;   // 16
constexpr int OFF_EW2  = 4648;   // 256
constexpr int OFF_EB2  = 4904;   // 16
constexpr int LDS_TOT  = 4920;

// ---------------- Kernel C: full per-element pipeline, weights in LDS ----------------
// Body loop structure = round-1 (register-resident proven); only operand source changed.
template<bool RECOMPUTE>
__global__ __launch_bounds__(256) void kC(
    const float* __restrict__ x, const float* __restrict__ zbuf,
    const float* __restrict__ noise, const float* __restrict__ fading,
    const float* __restrict__ ew1, const float* __restrict__ eb1,
    const float* __restrict__ ew2, const float* __restrict__ eb2,
    const float* __restrict__ bnp,
    const float* __restrict__ pc1w, const float* __restrict__ pc1b,
    const float* __restrict__ pc2w, const float* __restrict__ pc2b,
    const float* __restrict__ pc3w, const float* __restrict__ pc3b,
    const float* __restrict__ pc4w, const float* __restrict__ pc4b,
    const float* __restrict__ pc5w, const float* __restrict__ pc5b,
    const float* __restrict__ plw,  const float* __restrict__ plb,
    const float* __restrict__ dc1w, const float* __restrict__ dc1b,
    const float* __restrict__ dc2w, const float* __restrict__ dc2b,
    const float* __restrict__ dc3w, const float* __restrict__ dc3b,
    const float* __restrict__ dc4w, const float* __restrict__ dc4b,
    const float* __restrict__ dl1w, const float* __restrict__ dl1b,
    const float* __restrict__ dl2w, const float* __restrict__ dl2b,
    const float* __restrict__ dl3w, const float* __restrict__ dl3b,
    float* __restrict__ out, int B)
{
    __shared__ float W[LDS_TOT];
    int tid = threadIdx.x;

    // ---- stage weights into LDS ----
    {
        if (tid < 32)  W[OFF_BNP + tid] = bnp[tid];
        if (tid < 64)  W[OFF_PC1W + tid] = pc1w[tid];
        if (tid < 16)  W[OFF_PC1B + tid] = pc1b[tid];
        for (int j = tid; j < 512; j += 256) {               // pc2 -> [tap][o][ci]
            int o = j >> 5, r = j & 31, ci = r >> 1, tap = r & 1;
            W[OFF_PC2W + tap*256 + o*16 + ci] = pc2w[j];
        }
        if (tid < 16)  W[OFF_PC2B + tid] = pc2b[tid];
        for (int j = tid; j < 512; j += 256) W[OFF_PC3W + j] = pc3w[j];
        if (tid < 16)  W[OFF_PC3B + tid] = pc3b[tid];
        if (tid < 256) W[OFF_PC4W + tid] = pc4w[tid];
        if (tid < 16)  W[OFF_PC4B + tid] = pc4b[tid];
        for (int j = tid; j < 768; j += 256) {               // pc5 -> [g][o][ci]
            int o = j / 48, r = j - o*48, ci = r / 3, g = r - ci*3;
            W[OFF_PC5W + g*256 + o*16 + ci] = pc5w[j];
        }
        if (tid < 16)  W[OFF_PC5B + tid] = pc5b[tid];
        if (tid < 256) W[OFF_PLW + tid] = plw[tid];
        if (tid < 16)  W[OFF_PLB + tid] = plb[tid];
        if (tid < 8)   W[OFF_DC1W + tid] = dc1w[tid];
        if (tid < 8)   W[OFF_DC1B + tid] = dc1b[tid];
        if (tid < 128) W[OFF_DC2W + tid] = dc2w[tid];
        if (tid < 8)   W[OFF_DC2B + tid] = dc2b[tid];
        if (tid < 64)  W[OFF_DC3W + tid] = dc3w[tid];
        if (tid < 8)   W[OFF_DC3B + tid] = dc3b[tid];
        if (tid < 64)  W[OFF_DC4W + tid] = dc4w[tid];
        if (tid < 8)   W[OFF_DC4B + tid] = dc4b[tid];
        for (int j = tid; j < 1024; j += 256) {              // dl1 -> [o][t][c]
            int o = j >> 6, r = j & 63, c = r >> 3, t = r & 7;
            W[OFF_DL1W + o*64 + t*8 + c] = dl1w[j];
        }
        if (tid < 16)  W[OFF_DL1B + tid] = dl1b[tid];
        if (tid < 256) W[OFF_DL2W + tid] = dl2w[tid];
        if (tid < 16)  W[OFF_DL2B + tid] = dl2b[tid];
        if (tid < 256) W[OFF_DL3W + tid] = dl3w[tid];
        if (tid < 16)  W[OFF_DL3B + tid] = dl3b[tid];
        if (RECOMPUTE) {
            if (tid < 256) W[OFF_EW1 + tid] = ew1[tid];
            if (tid < 16)  W[OFF_EB1 + tid] = eb1[tid];
            if (tid < 256) W[OFF_EW2 + tid] = ew2[tid];
            if (tid < 16)  W[OFF_EB2 + tid] = eb2[tid];
        }
    }
    __syncthreads();

    int i = blockIdx.x * 256 + tid;
    if (i >= B) return;

    // ---- z (load or recompute) + BN affine ----
    float zn[16];
    if (RECOMPUTE) {
        float xv[16];
        const float4* xp = reinterpret_cast<const float4*>(x + (size_t)i * 16);
#pragma unroll
        for (int q = 0; q < 4; ++q) {
            float4 v = xp[q];
            xv[4*q+0] = v.x; xv[4*q+1] = v.y; xv[4*q+2] = v.z; xv[4*q+3] = v.w;
        }
        float h1[16];
#pragma unroll
        for (int o = 0; o < 16; ++o) {
            float a = W[OFF_EB1 + o];
#pragma unroll
            for (int k = 0; k < 16; ++k) a = fmaf(xv[k], W[OFF_EW1 + o*16+k], a);
            h1[o] = eluf(a);
        }
#pragma unroll
        for (int o = 0; o < 16; ++o) {
            float a = W[OFF_EB2 + o];
#pragma unroll
            for (int k = 0; k < 16; ++k) a = fmaf(h1[k], W[OFF_EW2 + o*16+k], a);
            zn[o] = fmaf(a, W[OFF_BNP + o], W[OFF_BNP + 16 + o]);
        }
    } else {
        const float4* zp = reinterpret_cast<const float4*>(zbuf + (size_t)i * 16);
#pragma unroll
        for (int q = 0; q < 4; ++q) {
            float4 v = zp[q];
            zn[4*q+0] = fmaf(v.x, W[OFF_BNP + 4*q+0], W[OFF_BNP + 16 + 4*q+0]);
            zn[4*q+1] = fmaf(v.y, W[OFF_BNP + 4*q+1], W[OFF_BNP + 16 + 4*q+1]);
            zn[4*q+2] = fmaf(v.z, W[OFF_BNP + 4*q+2], W[OFF_BNP + 16 + 4*q+2]);
            zn[4*q+3] = fmaf(v.w, W[OFF_BNP + 4*q+3], W[OFF_BNP + 16 + 4*q+3]);
        }
    }

    // ---- channel: 3-tap causal complex FIR + AWGN ----
    float f[6];
    {
        const float2* fp = reinterpret_cast<const float2*>(fading + (size_t)i * 6);
#pragma unroll
        for (int q = 0; q < 3; ++q) { float2 v = fp[q]; f[2*q] = v.x; f[2*q+1] = v.y; }
    }
    float cr[16];
#pragma unroll
    for (int n = 0; n < 8; ++n) {
        float re = f[0]*zn[2*n]   - f[1]*zn[2*n+1];
        float im = f[0]*zn[2*n+1] + f[1]*zn[2*n];
        if (n >= 1) { re += f[2]*zn[2*n-2] - f[3]*zn[2*n-1];
                      im += f[2]*zn[2*n-1] + f[3]*zn[2*n-2]; }
        if (n >= 2) { re += f[4]*zn[2*n-4] - f[5]*zn[2*n-3];
                      im += f[4]*zn[2*n-3] + f[5]*zn[2*n-4]; }
        cr[2*n] = re; cr[2*n+1] = im;
    }
    {
        const float4* np_ = reinterpret_cast<const float4*>(noise + (size_t)i * 16);
#pragma unroll
        for (int q = 0; q < 4; ++q) {
            float4 v = np_[q];
            cr[4*q+0] = fmaf(v.x, NSCALE, cr[4*q+0]);
            cr[4*q+1] = fmaf(v.y, NSCALE, cr[4*q+1]);
            cr[4*q+2] = fmaf(v.z, NSCALE, cr[4*q+2]);
            cr[4*q+3] = fmaf(v.w, NSCALE, cr[4*q+3]);
        }
    }

    // ---- p-convs (round-1 structure; p5 accumulated across g) ----
    float p5a[16];
#pragma unroll
    for (int o = 0; o < 16; ++o) p5a[o] = W[OFF_PC5B + o];

#pragma unroll
    for (int g = 0; g < 3; ++g) {
        float p1c[3][16];
#pragma unroll
        for (int c2 = 0; c2 < 3; ++c2) {
#pragma unroll
            for (int o = 0; o < 16; ++o) {
                float a = W[OFF_PC1B + o];
#pragma unroll
                for (int k = 0; k < 4; ++k) a = fmaf(W[OFF_PC1W + o*4+k], cr[4*g + c2 + k], a);
                p1c[c2][o] = reluf(a);
            }
        }
        float p2c[2][16];
#pragma unroll
        for (int c2 = 0; c2 < 2; ++c2) {
#pragma unroll
            for (int o = 0; o < 16; ++o) {
                float a = W[OFF_PC2B + o];
#pragma unroll
                for (int ci = 0; ci < 16; ++ci) {
                    a = fmaf(W[OFF_PC2W +       o*16 + ci], p1c[c2+0][ci], a);
                    a = fmaf(W[OFF_PC2W + 256 + o*16 + ci], p1c[c2+1][ci], a);
                }
                p2c[c2][o] = reluf(a);
            }
        }
        float p3c[16];
#pragma unroll
        for (int o = 0; o < 16; ++o) {
            float a = W[OFF_PC3B + o];
#pragma unroll
            for (int ci = 0; ci < 16; ++ci) {
                a = fmaf(W[OFF_PC3W + o*32 + ci*2 + 0], p2c[0][ci], a);
                a = fmaf(W[OFF_PC3W + o*32 + ci*2 + 1], p2c[1][ci], a);
            }
            p3c[o] = reluf(a);
        }
        float p4c[16];
#pragma unroll
        for (int o = 0; o < 16; ++o) {
            float a = W[OFF_PC4B + o];
#pragma unroll
            for (int ci = 0; ci < 16; ++ci) a = fmaf(W[OFF_PC4W + o*16 + ci], p3c[ci], a);
            p4c[o] = reluf(a);
        }
#pragma unroll
        for (int o = 0; o < 16; ++o) {
            float a = p5a[o];
#pragma unroll
            for (int ci = 0; ci < 16; ++ci)
                a = fmaf(W[OFF_PC5W + g*256 + o*16 + ci], p4c[ci], a);
            p5a[o] = a;
        }
    }

    float hh[16];
    {
        float p5r[16];
#pragma unroll
        for (int o = 0; o < 16; ++o) p5r[o] = reluf(p5a[o]);
#pragma unroll
        for (int o = 0; o < 16; ++o) {
            float a = W[OFF_PLB + o];
#pragma unroll
            for (int ci = 0; ci < 16; ++ci) a = fmaf(W[OFF_PLW + o*16 + ci], p5r[ci], a);
            hh[o] = a;
        }
    }

    // ---- complex equalizer t = cc / hh ----
    float tr[16];
#pragma unroll
    for (int n = 0; n < 8; ++n) {
        float a = cr[2*n], b = cr[2*n+1];
        float c = hh[2*n], d = hh[2*n+1];
        float inv = 1.0f / (c*c + d*d);
        tr[2*n]   = (a*c + b*d) * inv;
        tr[2*n+1] = (b*c - a*d) * inv;
    }

    // ---- d-convs, streamed column-wise into dl1 accumulation ----
    float y[16];
#pragma unroll
    for (int o = 0; o < 16; ++o) y[o] = W[OFF_DL1B + o];
#pragma unroll
    for (int t = 0; t < 8; ++t) {
        float d1a[8], d1b[8];
#pragma unroll
        for (int c = 0; c < 8; ++c) {
            d1a[c] = reluf(fmaf(W[OFF_DC1W + c], tr[2*t+0], W[OFF_DC1B + c]));
            d1b[c] = reluf(fmaf(W[OFF_DC1W + c], tr[2*t+1], W[OFF_DC1B + c]));
        }
        float d2[8];
#pragma unroll
        for (int c = 0; c < 8; ++c) {
            float a = W[OFF_DC2B + c];
#pragma unroll
            for (int ci = 0; ci < 8; ++ci) {
                a = fmaf(W[OFF_DC2W + c*16 + ci*2 + 0], d1a[ci], a);
                a = fmaf(W[OFF_DC2W + c*16 + ci*2 + 1], d1b[ci], a);
            }
            d2[c] = reluf(a);
        }
        float d3[8];
#pragma unroll
        for (int c = 0; c < 8; ++c) {
            float a = W[OFF_DC3B + c];
#pragma unroll
            for (int ci = 0; ci < 8; ++ci) a = fmaf(W[OFF_DC3W + c*8 + ci], d2[ci], a);
            d3[c] = reluf(a);
        }
        float d4[8];
#pragma unroll
        for (int c = 0; c < 8; ++c) {
            float a = W[OFF_DC4B + c];
#pragma unroll
            for (int ci = 0; ci < 8; ++ci) a = fmaf(W[OFF_DC4W + c*8 + ci], d3[ci], a);
            d4[c] = reluf(a);
        }
#pragma unroll
        for (int o = 0; o < 16; ++o) {
            float a = y[o];
#pragma unroll
            for (int c = 0; c < 8; ++c) a = fmaf(W[OFF_DL1W + o*64 + t*8 + c], d4[c], a);
            y[o] = a;
        }
    }
#pragma unroll
    for (int o = 0; o < 16; ++o) y[o] = reluf(y[o]);
    float h2[16];
#pragma unroll
    for (int o = 0; o < 16; ++o) {
        float a = W[OFF_DL2B + o];
#pragma unroll
        for (int ci = 0; ci < 16; ++ci) a = fmaf(W[OFF_DL2W + o*16 + ci], y[ci], a);
        h2[o] = eluf(a);
    }
    float o16[16];
#pragma unroll
    for (int o = 0; o < 16; ++o) {
        float a = W[OFF_DL3B + o];
#pragma unroll
        for (int ci = 0; ci < 16; ++ci) a = fmaf(W[OFF_DL3W + o*16 + ci], h2[ci], a);
        o16[o] = a;
    }
    float4* op = reinterpret_cast<float4*>(out + (size_t)i * 16);
    op[0] = make_float4(o16[0],  o16[1],  o16[2],  o16[3]);
    op[1] = make_float4(o16[4],  o16[5],  o16[6],  o16[7]);
    op[2] = make_float4(o16[8],  o16[9],  o16[10], o16[11]);
    op[3] = make_float4(o16[12], o16[13], o16[14], o16[15]);
}

extern "C" void kernel_launch(void* const* d_in, const int* in_sizes, int n_in,
                              void* d_out, int out_size, void* d_ws, size_t ws_size,
                              hipStream_t stream)
{
    const float* x      = (const float*)d_in[0];
    const float* noise  = (const float*)d_in[1];
    const float* fading = (const float*)d_in[2];
    const float* ew1  = (const float*)d_in[3];
    const float* eb1  = (const float*)d_in[4];
    const float* ew2  = (const float*)d_in[5];
    const float* eb2  = (const float*)d_in[6];
    const float* bng  = (const float*)d_in[7];
    const float* bnb  = (const float*)d_in[8];
    const float* pc1w = (const float*)d_in[9];
    const float* pc1b = (const float*)d_in[10];
    const float* pc2w = (const float*)d_in[11];
    const float* pc2b = (const float*)d_in[12];
    const float* pc3w = (const float*)d_in[13];
    const float* pc3b = (const float*)d_in[14];
    const float* pc4w = (const float*)d_in[15];
    const float* pc4b = (const float*)d_in[16];
    const float* pc5w = (const float*)d_in[17];
    const float* pc5b = (const float*)d_in[18];
    const float* plw  = (const float*)d_in[19];
    const float* plb  = (const float*)d_in[20];
    const float* dc1w = (const float*)d_in[21];
    const float* dc1b = (const float*)d_in[22];
    const float* dc2w = (const float*)d_in[23];
    const float* dc2b = (const float*)d_in[24];
    const float* dc3w = (const float*)d_in[25];
    const float* dc3b = (const float*)d_in[26];
    const float* dc4w = (const float*)d_in[27];
    const float* dc4b = (const float*)d_in[28];
    const float* dl1w = (const float*)d_in[29];
    const float* dl1b = (const float*)d_in[30];
    const float* dl2w = (const float*)d_in[31];
    const float* dl2b = (const float*)d_in[32];
    const float* dl3w = (const float*)d_in[33];
    const float* dl3b = (const float*)d_in[34];

    int B = in_sizes[0] / 16;
    int nblk = (B + 255) / 256;

    float* partials = (float*)d_ws;                 // nblk*32 floats
    float* bnp = partials + (size_t)nblk * 32;      // 32 floats (scale, shift)
    float* zbuf = bnp + 32;                         // B*16 floats (optional)
    size_t need = ((size_t)nblk * 32 + 32 + (size_t)B * 16) * sizeof(float);
    int have_z = (ws_size >= need) ? 1 : 0;

    kA<<<nblk, 256, 0, stream>>>(x, ew1, eb1, ew2, eb2, partials, zbuf, B, have_z);
    kB<<<1, 256, 0, stream>>>(partials, nblk, B, bng, bnb, bnp);
    if (have_z) {
        kC<false><<<nblk, 256, 0, stream>>>(x, zbuf, noise, fading,
                                            ew1, eb1, ew2, eb2, bnp,
                                            pc1w, pc1b, pc2w, pc2b, pc3w, pc3b, pc4w, pc4b, pc5w, pc5b,
                                            plw, plb,
                                            dc1w, dc1b, dc2w, dc2b, dc3w, dc3b, dc4w, dc4b,
                                            dl1w, dl1b, dl2w, dl2b, dl3w, dl3b,
                                            (float*)d_out, B);
    } else {
        kC<true><<<nblk, 256, 0, stream>>>(x, zbuf, noise, fading,
                                           ew1, eb1, ew2, eb2, bnp,
                                           pc1w, pc1b, pc2w, pc2b, pc3w, pc3b, pc4w, pc4b, pc5w, pc5b,
                                           plw, plb,
                                           dc1w, dc1b, dc2w, dc2b, dc3w, dc3b, dc4w, dc4b,
                                           dl1w, dl1b, dl2w, dl2b, dl3w, dl3b,
                                           (float*)d_out, B);
    }
}

// Round 4
// 306.493 us; speedup vs baseline: 7.6220x; 6.4694x over previous
//
#include <hip/hip_runtime.h>
#include <math.h>

#define NSCALE 0.44668359215096315f

__device__ __forceinline__ float eluf(float v)  { return v > 0.0f ? v : __expf(v) - 1.0f; }
__device__ __forceinline__ float reluf(float v) { return fmaxf(v, 0.0f); }

// ---------------- Kernel A: encoder -> z, per-block partial sums (stats only) ----------------
__global__ __launch_bounds__(256) void kA(const float* __restrict__ x,
                                          const float* __restrict__ ew1, const float* __restrict__ eb1,
                                          const float* __restrict__ ew2, const float* __restrict__ eb2,
                                          float* __restrict__ partials, int B)
{
    __shared__ float wsum[4][32];
    int tid = threadIdx.x;
    int i = blockIdx.x * 256 + tid;
    bool valid = i < B;
    float xv[16];
    if (valid) {
        const float4* xp = reinterpret_cast<const float4*>(x + (size_t)i * 16);
#pragma unroll
        for (int q = 0; q < 4; ++q) {
            float4 v = xp[q];
            xv[4*q+0] = v.x; xv[4*q+1] = v.y; xv[4*q+2] = v.z; xv[4*q+3] = v.w;
        }
    } else {
#pragma unroll
        for (int q = 0; q < 16; ++q) xv[q] = 0.0f;
    }

    float h1[16];
#pragma unroll
    for (int o = 0; o < 16; ++o) {
        float a = eb1[o];
#pragma unroll
        for (int k = 0; k < 16; ++k) a = fmaf(xv[k], ew1[o*16+k], a);
        h1[o] = eluf(a);
    }
    float z[16];
#pragma unroll
    for (int o = 0; o < 16; ++o) {
        float a = eb2[o];
#pragma unroll
        for (int k = 0; k < 16; ++k) a = fmaf(h1[k], ew2[o*16+k], a);
        z[o] = valid ? a : 0.0f;
    }

    int lane = tid & 63, wave = tid >> 6;
#pragma unroll
    for (int c = 0; c < 16; ++c) {
        float s = z[c];
        float q = z[c] * z[c];
#pragma unroll
        for (int m = 1; m < 64; m <<= 1) { s += __shfl_xor(s, m); q += __shfl_xor(q, m); }
        if (lane == 0) { wsum[wave][c] = s; wsum[wave][16 + c] = q; }
    }
    __syncthreads();
    if (tid < 32) {
        float t = wsum[0][tid] + wsum[1][tid] + wsum[2][tid] + wsum[3][tid];
        partials[(size_t)blockIdx.x * 32 + tid] = t;
    }
}

// ---------------- Kernel B: reduce partials -> BN affine ----------------
__global__ __launch_bounds__(256) void kB(const float* __restrict__ partials, int nblk, int B,
                                          const float* __restrict__ bng, const float* __restrict__ bnb,
                                          float* __restrict__ bnp)
{
    int tid = threadIdx.x;
    int q = tid >> 3, k = tid & 7;
    int chunk = (nblk + 7) / 8;
    int j0 = k * chunk;
    int j1 = j0 + chunk; if (j1 > nblk) j1 = nblk;
    double s = 0.0;
    for (int j = j0; j < j1; ++j) s += (double)partials[(size_t)j * 32 + q];
    s += __shfl_xor(s, 4);
    s += __shfl_xor(s, 2);
    s += __shfl_xor(s, 1);
    __shared__ double tot[32];
    if (k == 0) tot[q] = s;
    __syncthreads();
    if (tid < 16) {
        double mu  = tot[tid] / (double)B;
        double var = tot[16 + tid] / (double)B - mu * mu;
        double a = (double)bng[tid] / sqrt(var + 1e-5);
        double b = (double)bnb[tid] - mu * a;
        bnp[tid]      = (float)a;
        bnp[16 + tid] = (float)b;
    }
}

// ---------------- k1: encoder recompute + BN + FIR + noise -> cr ----------------
__global__ __launch_bounds__(256) void k1(const float* __restrict__ x,
                                          const float* __restrict__ fading,
                                          const float* __restrict__ noise,
                                          const float* __restrict__ ew1, const float* __restrict__ eb1,
                                          const float* __restrict__ ew2, const float* __restrict__ eb2,
                                          const float* __restrict__ bnp,
                                          float* __restrict__ crt, int B)
{
    int i = blockIdx.x * 256 + threadIdx.x;
    if (i >= B) return;

    float xv[16];
    {
        const float4* xp = reinterpret_cast<const float4*>(x + (size_t)i * 16);
#pragma unroll
        for (int q = 0; q < 4; ++q) {
            float4 v = xp[q];
            xv[4*q+0] = v.x; xv[4*q+1] = v.y; xv[4*q+2] = v.z; xv[4*q+3] = v.w;
        }
    }
    float h1[16];
#pragma unroll
    for (int o = 0; o < 16; ++o) {
        float a = eb1[o];
#pragma unroll
        for (int k = 0; k < 16; ++k) a = fmaf(xv[k], ew1[o*16+k], a);
        h1[o] = eluf(a);
    }
    float zn[16];
#pragma unroll
    for (int o = 0; o < 16; ++o) {
        float a = eb2[o];
#pragma unroll
        for (int k = 0; k < 16; ++k) a = fmaf(h1[k], ew2[o*16+k], a);
        zn[o] = fmaf(a, bnp[o], bnp[16 + o]);
    }

    float f[6];
    {
        const float2* fp = reinterpret_cast<const float2*>(fading + (size_t)i * 6);
#pragma unroll
        for (int q = 0; q < 3; ++q) { float2 v = fp[q]; f[2*q] = v.x; f[2*q+1] = v.y; }
    }
    float cr[16];
#pragma unroll
    for (int n = 0; n < 8; ++n) {
        float re = f[0]*zn[2*n]   - f[1]*zn[2*n+1];
        float im = f[0]*zn[2*n+1] + f[1]*zn[2*n];
        if (n >= 1) { re += f[2]*zn[2*n-2] - f[3]*zn[2*n-1];
                      im += f[2]*zn[2*n-1] + f[3]*zn[2*n-2]; }
        if (n >= 2) { re += f[4]*zn[2*n-4] - f[5]*zn[2*n-3];
                      im += f[4]*zn[2*n-3] + f[5]*zn[2*n-4]; }
        cr[2*n] = re; cr[2*n+1] = im;
    }
    {
        const float4* np_ = reinterpret_cast<const float4*>(noise + (size_t)i * 16);
#pragma unroll
        for (int q = 0; q < 4; ++q) {
            float4 v = np_[q];
            cr[4*q+0] = fmaf(v.x, NSCALE, cr[4*q+0]);
            cr[4*q+1] = fmaf(v.y, NSCALE, cr[4*q+1]);
            cr[4*q+2] = fmaf(v.z, NSCALE, cr[4*q+2]);
            cr[4*q+3] = fmaf(v.w, NSCALE, cr[4*q+3]);
        }
    }
    float4* op = reinterpret_cast<float4*>(crt + (size_t)i * 16);
    op[0] = make_float4(cr[0],  cr[1],  cr[2],  cr[3]);
    op[1] = make_float4(cr[4],  cr[5],  cr[6],  cr[7]);
    op[2] = make_float4(cr[8],  cr[9],  cr[10], cr[11]);
    op[3] = make_float4(cr[12], cr[13], cr[14], cr[15]);
}

// ---------------- k23: p-convs (rolled g-loop) + pl + equalizer; tr written in-place over cr ----------------
__global__ __launch_bounds__(256) void k23(float* __restrict__ crt,
    const float* __restrict__ pc1w, const float* __restrict__ pc1b,
    const float* __restrict__ pc2w, const float* __restrict__ pc2b,
    const float* __restrict__ pc3w, const float* __restrict__ pc3b,
    const float* __restrict__ pc4w, const float* __restrict__ pc4b,
    const float* __restrict__ pc5w, const float* __restrict__ pc5b,
    const float* __restrict__ plw,  const float* __restrict__ plb,
    int B)
{
    int i = blockIdx.x * 256 + threadIdx.x;
    if (i >= B) return;

    float p5a[16];
#pragma unroll
    for (int o = 0; o < 16; ++o) p5a[o] = pc5b[o];

#pragma unroll 1
    for (int g = 0; g < 3; ++g) {
        // runtime-g offset on GLOBAL pointer (not a private array) -> no demotion
        float crg[8];
        {
            const float4* cp = reinterpret_cast<const float4*>(crt + (size_t)i * 16 + 4 * g);
            float4 v0 = cp[0], v1 = cp[1];
            crg[0]=v0.x; crg[1]=v0.y; crg[2]=v0.z; crg[3]=v0.w;
            crg[4]=v1.x; crg[5]=v1.y; crg[6]=v1.z; crg[7]=v1.w;
        }
        float p1c[3][16];
#pragma unroll
        for (int c2 = 0; c2 < 3; ++c2) {
#pragma unroll
            for (int o = 0; o < 16; ++o) {
                float a = pc1b[o];
#pragma unroll
                for (int k = 0; k < 4; ++k) a = fmaf(pc1w[o*4+k], crg[c2+k], a);
                p1c[c2][o] = reluf(a);
            }
        }
        float p2c[2][16];
#pragma unroll
        for (int c2 = 0; c2 < 2; ++c2) {
#pragma unroll
            for (int o = 0; o < 16; ++o) {
                float a = pc2b[o];
#pragma unroll
                for (int ci = 0; ci < 16; ++ci) {
                    a = fmaf(pc2w[o*32+ci*2+0], p1c[c2+0][ci], a);
                    a = fmaf(pc2w[o*32+ci*2+1], p1c[c2+1][ci], a);
                }
                p2c[c2][o] = reluf(a);
            }
        }
        float p3[16];
#pragma unroll
        for (int o = 0; o < 16; ++o) {
            float a = pc3b[o];
#pragma unroll
            for (int ci = 0; ci < 16; ++ci) {
                a = fmaf(pc3w[o*32+ci*2+0], p2c[0][ci], a);
                a = fmaf(pc3w[o*32+ci*2+1], p2c[1][ci], a);
            }
            p3[o] = reluf(a);
        }
        float p4[16];
#pragma unroll
        for (int o = 0; o < 16; ++o) {
            float a = pc4b[o];
#pragma unroll
            for (int ci = 0; ci < 16; ++ci) a = fmaf(pc4w[o*16+ci], p3[ci], a);
            p4[o] = reluf(a);
        }
#pragma unroll
        for (int o = 0; o < 16; ++o) {
            float a = p5a[o];
#pragma unroll
            for (int ci = 0; ci < 16; ++ci)
                a = fmaf(pc5w[o*48 + ci*3 + g], p4[ci], a);   // runtime g on global index: OK
            p5a[o] = a;
        }
    }

    float p5r[16];
#pragma unroll
    for (int o = 0; o < 16; ++o) p5r[o] = reluf(p5a[o]);
    float hh[16];
#pragma unroll
    for (int o = 0; o < 16; ++o) {
        float a = plb[o];
#pragma unroll
        for (int ci = 0; ci < 16; ++ci) a = fmaf(plw[o*16+ci], p5r[ci], a);
        hh[o] = a;
    }

    // reload cr, equalize, store tr in place
    float cr[16];
    {
        const float4* cp = reinterpret_cast<const float4*>(crt + (size_t)i * 16);
#pragma unroll
        for (int q = 0; q < 4; ++q) {
            float4 v = cp[q];
            cr[4*q+0] = v.x; cr[4*q+1] = v.y; cr[4*q+2] = v.z; cr[4*q+3] = v.w;
        }
    }
    float tr[16];
#pragma unroll
    for (int n = 0; n < 8; ++n) {
        float a = cr[2*n], b = cr[2*n+1];
        float c = hh[2*n], d = hh[2*n+1];
        float inv = 1.0f / (c*c + d*d);
        tr[2*n]   = (a*c + b*d) * inv;
        tr[2*n+1] = (b*c - a*d) * inv;
    }
    float4* op = reinterpret_cast<float4*>(crt + (size_t)i * 16);
    op[0] = make_float4(tr[0],  tr[1],  tr[2],  tr[3]);
    op[1] = make_float4(tr[4],  tr[5],  tr[6],  tr[7]);
    op[2] = make_float4(tr[8],  tr[9],  tr[10], tr[11]);
    op[3] = make_float4(tr[12], tr[13], tr[14], tr[15]);
}

// ---------------- k4: d-convs (rolled t-loop) + dl1/dl2/dl3 -> out ----------------
__global__ __launch_bounds__(256) void k4(const float* __restrict__ trt,
    const float* __restrict__ dc1w, const float* __restrict__ dc1b,
    const float* __restrict__ dc2w, const float* __restrict__ dc2b,
    const float* __restrict__ dc3w, const float* __restrict__ dc3b,
    const float* __restrict__ dc4w, const float* __restrict__ dc4b,
    const float* __restrict__ dl1w, const float* __restrict__ dl1b,
    const float* __restrict__ dl2w, const float* __restrict__ dl2b,
    const float* __restrict__ dl3w, const float* __restrict__ dl3b,
    float* __restrict__ out, int B)
{
    int i = blockIdx.x * 256 + threadIdx.x;
    if (i >= B) return;

    float y[16];
#pragma unroll
    for (int o = 0; o < 16; ++o) y[o] = dl1b[o];

#pragma unroll 1
    for (int t = 0; t < 8; ++t) {
        float2 tv = *reinterpret_cast<const float2*>(trt + (size_t)i * 16 + 2 * t); // runtime t on global: OK
        float d1a[8], d1b[8];
#pragma unroll
        for (int c = 0; c < 8; ++c) {
            d1a[c] = reluf(fmaf(dc1w[c], tv.x, dc1b[c]));
            d1b[c] = reluf(fmaf(dc1w[c], tv.y, dc1b[c]));
        }
        float d2[8];
#pragma unroll
        for (int c = 0; c < 8; ++c) {
            float a = dc2b[c];
#pragma unroll
            for (int ci = 0; ci < 8; ++ci) {
                a = fmaf(dc2w[c*16+ci*2+0], d1a[ci], a);
                a = fmaf(dc2w[c*16+ci*2+1], d1b[ci], a);
            }
            d2[c] = reluf(a);
        }
        float d3[8];
#pragma unroll
        for (int c = 0; c < 8; ++c) {
            float a = dc3b[c];
#pragma unroll
            for (int ci = 0; ci < 8; ++ci) a = fmaf(dc3w[c*8+ci], d2[ci], a);
            d3[c] = reluf(a);
        }
        float d4[8];
#pragma unroll
        for (int c = 0; c < 8; ++c) {
            float a = dc4b[c];
#pragma unroll
            for (int ci = 0; ci < 8; ++ci) a = fmaf(dc4w[c*8+ci], d3[ci], a);
            d4[c] = reluf(a);
        }
#pragma unroll
        for (int o = 0; o < 16; ++o) {
            float a = y[o];
#pragma unroll
            for (int c = 0; c < 8; ++c) a = fmaf(dl1w[o*64 + c*8 + t], d4[c], a); // runtime t on global: OK
            y[o] = a;
        }
    }
#pragma unroll
    for (int o = 0; o < 16; ++o) y[o] = reluf(y[o]);
    float h2[16];
#pragma unroll
    for (int o = 0; o < 16; ++o) {
        float a = dl2b[o];
#pragma unroll
        for (int ci = 0; ci < 16; ++ci) a = fmaf(dl2w[o*16+ci], y[ci], a);
        h2[o] = eluf(a);
    }
    float o16[16];
#pragma unroll
    for (int o = 0; o < 16; ++o) {
        float a = dl3b[o];
#pragma unroll
        for (int ci = 0; ci < 16; ++ci) a = fmaf(dl3w[o*16+ci], h2[ci], a);
        o16[o] = a;
    }
    float4* op = reinterpret_cast<float4*>(out + (size_t)i * 16);
    op[0] = make_float4(o16[0],  o16[1],  o16[2],  o16[3]);
    op[1] = make_float4(o16[4],  o16[5],  o16[6],  o16[7]);
    op[2] = make_float4(o16[8],  o16[9],  o16[10], o16[11]);
    op[3] = make_float4(o16[12], o16[13], o16[14], o16[15]);
}

extern "C" void kernel_launch(void* const* d_in, const int* in_sizes, int n_in,
                              void* d_out, int out_size, void* d_ws, size_t ws_size,
                              hipStream_t stream)
{
    const float* x      = (const float*)d_in[0];
    const float* noise  = (const float*)d_in[1];
    const float* fading = (const float*)d_in[2];
    const float* ew1  = (const float*)d_in[3];
    const float* eb1  = (const float*)d_in[4];
    const float* ew2  = (const float*)d_in[5];
    const float* eb2  = (const float*)d_in[6];
    const float* bng  = (const float*)d_in[7];
    const float* bnb  = (const float*)d_in[8];
    const float* pc1w = (const float*)d_in[9];
    const float* pc1b = (const float*)d_in[10];
    const float* pc2w = (const float*)d_in[11];
    const float* pc2b = (const float*)d_in[12];
    const float* pc3w = (const float*)d_in[13];
    const float* pc3b = (const float*)d_in[14];
    const float* pc4w = (const float*)d_in[15];
    const float* pc4b = (const float*)d_in[16];
    const float* pc5w = (const float*)d_in[17];
    const float* pc5b = (const float*)d_in[18];
    const float* plw  = (const float*)d_in[19];
    const float* plb  = (const float*)d_in[20];
    const float* dc1w = (const float*)d_in[21];
    const float* dc1b = (const float*)d_in[22];
    const float* dc2w = (const float*)d_in[23];
    const float* dc2b = (const float*)d_in[24];
    const float* dc3w = (const float*)d_in[25];
    const float* dc3b = (const float*)d_in[26];
    const float* dc4w = (const float*)d_in[27];
    const float* dc4b = (const float*)d_in[28];
    const float* dl1w = (const float*)d_in[29];
    const float* dl1b = (const float*)d_in[30];
    const float* dl2w = (const float*)d_in[31];
    const float* dl2b = (const float*)d_in[32];
    const float* dl3w = (const float*)d_in[33];
    const float* dl3b = (const float*)d_in[34];

    int B = in_sizes[0] / 16;
    int nblk = (B + 255) / 256;

    float* partials = (float*)d_ws;                 // nblk*32 floats
    float* bnp = partials + (size_t)nblk * 32;      // 32 floats
    float* crt = bnp + 32;                          // B*16 floats (cr, then tr in-place)

    kA<<<nblk, 256, 0, stream>>>(x, ew1, eb1, ew2, eb2, partials, B);
    kB<<<1, 256, 0, stream>>>(partials, nblk, B, bng, bnb, bnp);
    k1<<<nblk, 256, 0, stream>>>(x, fading, noise, ew1, eb1, ew2, eb2, bnp, crt, B);
    k23<<<nblk, 256, 0, stream>>>(crt,
                                  pc1w, pc1b, pc2w, pc2b, pc3w, pc3b, pc4w, pc4b, pc5w, pc5b,
                                  plw, plb, B);
    k4<<<nblk, 256, 0, stream>>>(crt,
                                 dc1w, dc1b, dc2w, dc2b, dc3w, dc3b, dc4w, dc4b,
                                 dl1w, dl1b, dl2w, dl2b, dl3w, dl3b,
                                 (float*)d_out, B);
}